// Round 6
// baseline (638.521 us; speedup 1.0000x reference)
//
#include <hip/hip_runtime.h>

// Problem constants (fixed by setup_inputs)
#define B      8
#define L      4096
#define D      1024
#define NB     4
#define BS     (L / NB)         // 1024 rows per (b, nb) block
#define BN     (B * NB)         // 32 (b, nb) groups
#define SPLITS 64               // row splits for pooling
#define ROWS_PER (BS / SPLITS)  // 16 rows per partial block

typedef __attribute__((ext_vector_type(4))) float f32x4;

// ---------------- Kernel 1: partial pooling + last-block reduce ----------------
// grid: BN*SPLITS = 2048 blocks, 256 threads. Each block sums 16 rows x 1024 cols.
// The last block to finish within each bn folds the 64 partials -> pooled[bn].
__global__ void pool_partial_reduce(const float* __restrict__ x, float* __restrict__ partial,
                                    float* __restrict__ pooled, unsigned int* __restrict__ cnt) {
    int gid = blockIdx.x;
    int s   = gid & (SPLITS - 1);
    int bn  = gid >> 6;            // /SPLITS
    int t   = threadIdx.x;         // float4 column

    const float4* xb = (const float4*)(x + (size_t)bn * BS * D + (size_t)s * ROWS_PER * D);
    float4 acc = make_float4(0.f, 0.f, 0.f, 0.f);
    #pragma unroll
    for (int r = 0; r < ROWS_PER; ++r) {
        float4 v = xb[(size_t)r * (D / 4) + t];
        acc.x += v.x; acc.y += v.y; acc.z += v.z; acc.w += v.w;
    }
    ((float4*)(partial + ((size_t)bn * SPLITS + s) * D))[t] = acc;

    // release: make this block's partial visible device-wide, then count in
    __threadfence();
    __shared__ int is_last;
    if (t == 0) is_last = (atomicAdd(&cnt[bn], 1u) == SPLITS - 1);
    __syncthreads();

    if (is_last) {
        __threadfence();  // acquire: see all other blocks' partials
        const float4* p = (const float4*)(partial + (size_t)bn * SPLITS * D);
        float4 a = make_float4(0.f, 0.f, 0.f, 0.f);
        #pragma unroll 8
        for (int s2 = 0; s2 < SPLITS; ++s2) {
            float4 v = p[(size_t)s2 * (D / 4) + t];
            a.x += v.x; a.y += v.y; a.z += v.z; a.w += v.w;
        }
        const float inv = 1.0f / (float)BS;
        ((float4*)(pooled + (size_t)bn * D))[t] =
            make_float4(a.x * inv, a.y * inv, a.z * inv, a.w * inv);
    }
}

// ---------------- Kernel 2: gate = sigmoid(pooled @ W^T + b) ----------------
// grid: BN*32 = 1024 blocks; block = (bn, 32-e tile), 256 threads = 4 waves.
// Wave computes 8 e's, 4 at a time (independent shfl chains for ILP).
__global__ void gate_kernel(const float* __restrict__ pooled, const float* __restrict__ W,
                            const float* __restrict__ bias, float* __restrict__ gate) {
    int blk  = blockIdx.x;
    int bn   = blk >> 5;          // 0..31
    int et   = blk & 31;          // 32 tiles of 32 e's
    int t    = threadIdx.x;
    int wv   = t >> 6;
    int lane = t & 63;

    const float4* p4 = (const float4*)(pooled + (size_t)bn * D);
    float4 pf[4];
    #pragma unroll
    for (int c = 0; c < 4; ++c) pf[c] = p4[c * 64 + lane];

    const int ewv = et * 32 + wv * 8;
    #pragma unroll
    for (int i = 0; i < 8; i += 4) {
        float s0 = 0.f, s1 = 0.f, s2 = 0.f, s3 = 0.f;
        #pragma unroll
        for (int c = 0; c < 4; ++c) {
            float4 w0 = ((const float4*)(W + (size_t)(ewv + i + 0) * D))[c * 64 + lane];
            float4 w1 = ((const float4*)(W + (size_t)(ewv + i + 1) * D))[c * 64 + lane];
            float4 w2 = ((const float4*)(W + (size_t)(ewv + i + 2) * D))[c * 64 + lane];
            float4 w3 = ((const float4*)(W + (size_t)(ewv + i + 3) * D))[c * 64 + lane];
            float4 pp = pf[c];
            s0 += w0.x * pp.x + w0.y * pp.y + w0.z * pp.z + w0.w * pp.w;
            s1 += w1.x * pp.x + w1.y * pp.y + w1.z * pp.z + w1.w * pp.w;
            s2 += w2.x * pp.x + w2.y * pp.y + w2.z * pp.z + w2.w * pp.w;
            s3 += w3.x * pp.x + w3.y * pp.y + w3.z * pp.z + w3.w * pp.w;
        }
        #pragma unroll
        for (int off = 32; off; off >>= 1) {
            s0 += __shfl_down(s0, off);
            s1 += __shfl_down(s1, off);
            s2 += __shfl_down(s2, off);
            s3 += __shfl_down(s3, off);
        }
        if (lane == 0) {
            int e = ewv + i;
            gate[(size_t)bn * D + e + 0] = 1.0f / (1.0f + __expf(-(s0 + bias[e + 0])));
            gate[(size_t)bn * D + e + 1] = 1.0f / (1.0f + __expf(-(s1 + bias[e + 1])));
            gate[(size_t)bn * D + e + 2] = 1.0f / (1.0f + __expf(-(s2 + bias[e + 2])));
            gate[(size_t)bn * D + e + 3] = 1.0f / (1.0f + __expf(-(s3 + bias[e + 3])));
        }
    }
}

// ---------------- Kernel 3: out = x * gate ----------------
// grid: 8192 blocks; block -> (bn, 4-row slice). Gate loaded once per thread;
// nontemporal stores keep x L3-resident for this read.
__global__ void apply_gate(const float* __restrict__ x, const float* __restrict__ gate,
                           float* __restrict__ out) {
    int blk = blockIdx.x;
    int bn  = blk >> 8;           // 0..31
    int s   = blk & 255;          // 256 slices of 4 rows
    int t   = threadIdx.x;        // float4 column

    float4 gv = ((const float4*)(gate + (size_t)bn * D))[t];
    const float4* xb = (const float4*)(x + ((size_t)bn * BS + (size_t)s * 4) * D);
    float4* ob = (float4*)(out + ((size_t)bn * BS + (size_t)s * 4) * D);
    #pragma unroll
    for (int r = 0; r < 4; ++r) {
        float4 v = xb[(size_t)r * (D / 4) + t];
        float4 o = make_float4(v.x * gv.x, v.y * gv.y, v.z * gv.z, v.w * gv.w);
        __builtin_nontemporal_store(*(const f32x4*)&o, (f32x4*)&ob[(size_t)r * (D / 4) + t]);
    }
}

extern "C" void kernel_launch(void* const* d_in, const int* in_sizes, int n_in,
                              void* d_out, int out_size, void* d_ws, size_t ws_size,
                              hipStream_t stream) {
    const float* x    = (const float*)d_in[0];
    const float* W    = (const float*)d_in[1];
    const float* bias = (const float*)d_in[2];
    float* out        = (float*)d_out;

    // Workspace layout (floats):
    //   partial: BN*SPLITS*D = 2M floats (8 MB)
    //   pooled : BN*D        = 32768 floats (128 KB)
    //   gate   : BN*D        = 32768 floats (128 KB)
    //   cnt    : BN uints    (zeroed each call via async memset - graph-safe node)
    float* partial = (float*)d_ws;
    float* pooled  = partial + (size_t)BN * SPLITS * D;
    float* gate    = pooled + (size_t)BN * D;
    unsigned int* cnt = (unsigned int*)(gate + (size_t)BN * D);

    hipMemsetAsync(cnt, 0, BN * sizeof(unsigned int), stream);
    hipLaunchKernelGGL(pool_partial_reduce, dim3(BN * SPLITS), dim3(256), 0, stream,
                       x, partial, pooled, cnt);
    hipLaunchKernelGGL(gate_kernel, dim3(BN * 32), dim3(256), 0, stream, pooled, W, bias, gate);
    hipLaunchKernelGGL(apply_gate,  dim3(8192),    dim3(256), 0, stream, x, gate, out);
}

// Round 8
// 269.488 us; speedup vs baseline: 2.3694x; 2.3694x over previous
//
#include <hip/hip_runtime.h>

// Problem constants (fixed by setup_inputs)
#define B      8
#define L      4096
#define D      1024
#define NB     4
#define BS     (L / NB)         // 1024 rows per (b, nb) block
#define BN     (B * NB)         // 32 (b, nb) groups
#define SPLITS 64               // row splits for pooling
#define ROWS_PER (BS / SPLITS)  // 16 rows per partial block

typedef __attribute__((ext_vector_type(4))) float f32x4;

// ---------------- Kernel 1: partial pooling sums ----------------
// grid: BN*SPLITS = 2048 blocks, 256 threads -> full occupancy, saturates HBM read.
// NOTE (R6 lesson): do NOT fold the reduce in via last-block-done atomics —
// cross-XCD contention on the counter line cost 438 us (2.3% BW). Separate
// kernel launch is ~5 us total.
__global__ void pool_partial(const float* __restrict__ x, float* __restrict__ partial) {
    int gid = blockIdx.x;
    int s   = gid & (SPLITS - 1);
    int bn  = gid >> 6;            // /SPLITS
    int t   = threadIdx.x;         // float4 column

    const float4* xb = (const float4*)(x + (size_t)bn * BS * D + (size_t)s * ROWS_PER * D);
    float4 acc = make_float4(0.f, 0.f, 0.f, 0.f);
    #pragma unroll
    for (int r = 0; r < ROWS_PER; ++r) {
        float4 v = xb[(size_t)r * (D / 4) + t];
        acc.x += v.x; acc.y += v.y; acc.z += v.z; acc.w += v.w;
    }
    ((float4*)(partial + ((size_t)bn * SPLITS + s) * D))[t] = acc;
}

// ---------------- Kernel 2: fold partials -> pooled (mean) ----------------
// grid: BN = 32 blocks, 256 threads; 8 MB read (L2-resident), trivial.
__global__ void pool_reduce(const float* __restrict__ partial, float* __restrict__ pooled) {
    int bn = blockIdx.x;
    int t  = threadIdx.x;
    const float4* p = (const float4*)(partial + (size_t)bn * SPLITS * D);
    float4 acc = make_float4(0.f, 0.f, 0.f, 0.f);
    #pragma unroll 8
    for (int s = 0; s < SPLITS; ++s) {
        float4 v = p[(size_t)s * (D / 4) + t];
        acc.x += v.x; acc.y += v.y; acc.z += v.z; acc.w += v.w;
    }
    const float inv = 1.0f / (float)BS;
    ((float4*)(pooled + (size_t)bn * D))[t] =
        make_float4(acc.x * inv, acc.y * inv, acc.z * inv, acc.w * inv);
}

// ---------------- Kernel 3: gate = sigmoid(pooled @ W^T + b) ----------------
// grid: BN*32 = 1024 blocks; block = (bn, 32-e tile), 256 threads = 4 waves.
// Wave computes 8 e's, 4 at a time (independent shfl chains for ILP).
__global__ void gate_kernel(const float* __restrict__ pooled, const float* __restrict__ W,
                            const float* __restrict__ bias, float* __restrict__ gate) {
    int blk  = blockIdx.x;
    int bn   = blk >> 5;          // 0..31
    int et   = blk & 31;          // 32 tiles of 32 e's
    int t    = threadIdx.x;
    int wv   = t >> 6;
    int lane = t & 63;

    const float4* p4 = (const float4*)(pooled + (size_t)bn * D);
    float4 pf[4];
    #pragma unroll
    for (int c = 0; c < 4; ++c) pf[c] = p4[c * 64 + lane];

    const int ewv = et * 32 + wv * 8;
    #pragma unroll
    for (int i = 0; i < 8; i += 4) {
        float s0 = 0.f, s1 = 0.f, s2 = 0.f, s3 = 0.f;
        #pragma unroll
        for (int c = 0; c < 4; ++c) {
            float4 w0 = ((const float4*)(W + (size_t)(ewv + i + 0) * D))[c * 64 + lane];
            float4 w1 = ((const float4*)(W + (size_t)(ewv + i + 1) * D))[c * 64 + lane];
            float4 w2 = ((const float4*)(W + (size_t)(ewv + i + 2) * D))[c * 64 + lane];
            float4 w3 = ((const float4*)(W + (size_t)(ewv + i + 3) * D))[c * 64 + lane];
            float4 pp = pf[c];
            s0 += w0.x * pp.x + w0.y * pp.y + w0.z * pp.z + w0.w * pp.w;
            s1 += w1.x * pp.x + w1.y * pp.y + w1.z * pp.z + w1.w * pp.w;
            s2 += w2.x * pp.x + w2.y * pp.y + w2.z * pp.z + w2.w * pp.w;
            s3 += w3.x * pp.x + w3.y * pp.y + w3.z * pp.z + w3.w * pp.w;
        }
        #pragma unroll
        for (int off = 32; off; off >>= 1) {
            s0 += __shfl_down(s0, off);
            s1 += __shfl_down(s1, off);
            s2 += __shfl_down(s2, off);
            s3 += __shfl_down(s3, off);
        }
        if (lane == 0) {
            int e = ewv + i;
            gate[(size_t)bn * D + e + 0] = 1.0f / (1.0f + __expf(-(s0 + bias[e + 0])));
            gate[(size_t)bn * D + e + 1] = 1.0f / (1.0f + __expf(-(s1 + bias[e + 1])));
            gate[(size_t)bn * D + e + 2] = 1.0f / (1.0f + __expf(-(s2 + bias[e + 2])));
            gate[(size_t)bn * D + e + 3] = 1.0f / (1.0f + __expf(-(s3 + bias[e + 3])));
        }
    }
}

// ---------------- Kernel 4: out = x * gate ----------------
// grid: 8192 blocks; block -> (bn, 4-row slice). Gate loaded once per thread;
// nontemporal stores keep x L3-resident for this read.
__global__ void apply_gate(const float* __restrict__ x, const float* __restrict__ gate,
                           float* __restrict__ out) {
    int blk = blockIdx.x;
    int bn  = blk >> 8;           // 0..31
    int s   = blk & 255;          // 256 slices of 4 rows
    int t   = threadIdx.x;        // float4 column

    float4 gv = ((const float4*)(gate + (size_t)bn * D))[t];
    const float4* xb = (const float4*)(x + ((size_t)bn * BS + (size_t)s * 4) * D);
    float4* ob = (float4*)(out + ((size_t)bn * BS + (size_t)s * 4) * D);
    #pragma unroll
    for (int r = 0; r < 4; ++r) {
        float4 v = xb[(size_t)r * (D / 4) + t];
        float4 o = make_float4(v.x * gv.x, v.y * gv.y, v.z * gv.z, v.w * gv.w);
        __builtin_nontemporal_store(*(const f32x4*)&o, (f32x4*)&ob[(size_t)r * (D / 4) + t]);
    }
}

extern "C" void kernel_launch(void* const* d_in, const int* in_sizes, int n_in,
                              void* d_out, int out_size, void* d_ws, size_t ws_size,
                              hipStream_t stream) {
    const float* x    = (const float*)d_in[0];
    const float* W    = (const float*)d_in[1];
    const float* bias = (const float*)d_in[2];
    float* out        = (float*)d_out;

    // Workspace layout (floats):
    //   partial: BN*SPLITS*D = 2M floats (8 MB)
    //   pooled : BN*D        = 32768 floats (128 KB)
    //   gate   : BN*D        = 32768 floats (128 KB)
    float* partial = (float*)d_ws;
    float* pooled  = partial + (size_t)BN * SPLITS * D;
    float* gate    = pooled + (size_t)BN * D;

    hipLaunchKernelGGL(pool_partial, dim3(BN * SPLITS), dim3(256), 0, stream, x, partial);
    hipLaunchKernelGGL(pool_reduce,  dim3(BN),          dim3(256), 0, stream, partial, pooled);
    hipLaunchKernelGGL(gate_kernel,  dim3(BN * 32),     dim3(256), 0, stream, pooled, W, bias, gate);
    hipLaunchKernelGGL(apply_gate,   dim3(8192),        dim3(256), 0, stream, x, gate, out);
}